// Round 1
// baseline (763.329 us; speedup 1.0000x reference)
//
#include <hip/hip_runtime.h>
#include <hip/hip_bf16.h>

#define E_EDGES   800000
#define NN_NODES  50000
#define NODE_DIM  128
#define EDGE_DIM  64
#define KDIM      320
#define NTOT      256      // val(128) || gate(128)
#define BM        128      // edges per block
#define BK        64       // K chunk
#define SA        72       // padded LDS row stride in f16 elems (144 B = 36 dwords)
#define THREADS   512

typedef _Float16 half8 __attribute__((ext_vector_type(8)));
typedef float    f32x4 __attribute__((ext_vector_type(4)));

__device__ __forceinline__ unsigned short f2h(float f) {
    _Float16 h = (_Float16)f;
    return __builtin_bit_cast(unsigned short, h);
}

// ---- cast x (N_NODES x 128 fp32) -> f16 ----
__global__ void cast_x_kernel(const float* __restrict__ src,
                              unsigned short* __restrict__ dst, int n4) {
    int i = blockIdx.x * blockDim.x + threadIdx.x;
    if (i < n4) {
        float4 f = ((const float4*)src)[i];
        ushort4 o;
        o.x = f2h(f.x); o.y = f2h(f.y); o.z = f2h(f.z); o.w = f2h(f.w);
        ((ushort4*)dst)[i] = o;
    }
}

// ---- cast W_val,W_mul (each 128x320 fp32) -> combined f16 [256][320] ----
__global__ void cast_w_kernel(const float* __restrict__ wv,
                              const float* __restrict__ wm,
                              unsigned short* __restrict__ dst) {
    int i = blockIdx.x * blockDim.x + threadIdx.x;       // 4 elems each
    const int total4 = (2 * NODE_DIM * KDIM) / 4;        // 20480
    if (i < total4) {
        const int half4 = (NODE_DIM * KDIM) / 4;         // 10240
        const float* src = (i < half4) ? wv : wm;
        int j = (i < half4) ? i : i - half4;
        float4 f = ((const float4*)src)[j];
        ushort4 o;
        o.x = f2h(f.x); o.y = f2h(f.y); o.z = f2h(f.z); o.w = f2h(f.w);
        ((ushort4*)dst)[i] = o;
    }
}

// ---- fused gather + dual-GEMM + softplus*sigmoid + atomic scatter ----
__global__ void __launch_bounds__(THREADS)
cgc_main(const unsigned short* __restrict__ xh,   // [NN][128] f16 bits
         const int* __restrict__ ei,              // [2][E]
         const float* __restrict__ ef,            // [E][64] fp32
         const unsigned short* __restrict__ Wc,   // [256][320] f16 bits
         const float* __restrict__ bval,          // [128]
         const float* __restrict__ bmul,          // [128]
         float* __restrict__ out)                 // [NN][128] fp32 (zeroed)
{
    __shared__ unsigned short As[BM * SA];    // 18432 B
    __shared__ unsigned short Bs[NTOT * SA];  // 36864 B
    __shared__ int sIdx[BM];
    __shared__ int rIdx[BM];

    const int tid  = threadIdx.x;
    const int e0   = blockIdx.x * BM;
    const int lane = tid & 63;
    const int wid  = tid >> 6;      // 0..7
    const int wm   = wid & 1;       // M half: rows [wm*64, wm*64+64)
    const int wn   = wid >> 1;      // 0..3: N strip of 32 output cols
    const int q    = lane >> 4;     // quad
    const int l16  = lane & 15;

    if (tid < BM) {
        sIdx[tid] = ei[e0 + tid];
        rIdx[tid] = ei[E_EDGES + e0 + tid];
    }

    f32x4 acc[4][4];
    const f32x4 zero4 = {0.f, 0.f, 0.f, 0.f};
#pragma unroll
    for (int mt = 0; mt < 4; ++mt)
#pragma unroll
        for (int nt = 0; nt < 4; ++nt) acc[mt][nt] = zero4;

    for (int c = 0; c < 5; ++c) {
        __syncthreads();   // idx ready (c=0) / prev compute done reading LDS
        // ---- stage A chunk: 128 rows x 64 k (f16) ----
        if (c < 4) {
            const int kcol = (c & 1) * 64;   // column offset within x row
#pragma unroll
            for (int i = 0; i < 2; ++i) {
                int u = tid + i * THREADS;   // 0..1023
                int row = u >> 3, seg = u & 7;
                int node = (c < 2) ? sIdx[row] : rIdx[row];
                uint4 v = *(const uint4*)(xh + (size_t)node * NODE_DIM + kcol + seg * 8);
                *(uint4*)(&As[row * SA + seg * 8]) = v;
            }
        } else {
            // edge_ft: fp32 -> f16 convert on the fly
#pragma unroll
            for (int i = 0; i < 2; ++i) {
                int u = tid + i * THREADS;   // 0..1023 ; 8 floats per unit
                int row = u >> 3, seg = u & 7;
                const float* s = ef + (size_t)(e0 + row) * EDGE_DIM + seg * 8;
                float4 f0 = ((const float4*)s)[0];
                float4 f1 = ((const float4*)s)[1];
                uint4 v;
                v.x = (unsigned)f2h(f0.x) | ((unsigned)f2h(f0.y) << 16);
                v.y = (unsigned)f2h(f0.z) | ((unsigned)f2h(f0.w) << 16);
                v.z = (unsigned)f2h(f1.x) | ((unsigned)f2h(f1.y) << 16);
                v.w = (unsigned)f2h(f1.z) | ((unsigned)f2h(f1.w) << 16);
                *(uint4*)(&As[row * SA + seg * 8]) = v;
            }
        }
        // ---- stage B chunk: 256 rows x 64 k (f16, from L2-resident Wc) ----
        {
            const int kOff = c * BK;
#pragma unroll
            for (int i = 0; i < 4; ++i) {
                int u = tid + i * THREADS;   // 0..2047
                int n = u >> 3, seg = u & 7;
                uint4 v = *(const uint4*)(Wc + n * KDIM + kOff + seg * 8);
                *(uint4*)(&Bs[n * SA + seg * 8]) = v;
            }
        }
        __syncthreads();
        // ---- compute: 2 k-steps x 16 mfma ----
#pragma unroll
        for (int ks = 0; ks < BK; ks += 32) {
            half8 a[4], b[4];
#pragma unroll
            for (int mt = 0; mt < 4; ++mt)
                a[mt] = *(const half8*)(&As[(wm * 64 + mt * 16 + l16) * SA + ks + q * 8]);
            const int nb0 = wn * 32;
            const int nbase[4] = { nb0, nb0 + 16, 128 + nb0, 128 + nb0 + 16 };
#pragma unroll
            for (int nt = 0; nt < 4; ++nt)
                b[nt] = *(const half8*)(&Bs[(nbase[nt] + l16) * SA + ks + q * 8]);
#pragma unroll
            for (int mt = 0; mt < 4; ++mt)
#pragma unroll
                for (int nt = 0; nt < 4; ++nt)
                    acc[mt][nt] = __builtin_amdgcn_mfma_f32_16x16x32_f16(
                        a[mt], b[nt], acc[mt][nt], 0, 0, 0);
        }
    }

    // ---- epilogue: msg = softplus(val+bv) * sigmoid(gate+bm); atomic scatter ----
#pragma unroll
    for (int ct = 0; ct < 2; ++ct) {
        const int col = wn * 32 + ct * 16 + l16;
        const float bv = bval[col];
        const float bm = bmul[col];
#pragma unroll
        for (int mt = 0; mt < 4; ++mt) {
#pragma unroll
            for (int r = 0; r < 4; ++r) {
                float v = acc[mt][ct][r] + bv;
                float g = acc[mt][ct + 2][r] + bm;
                float sp  = fmaxf(v, 0.f) + log1pf(expf(-fabsf(v)));
                float sig = 1.f / (1.f + expf(-g));
                float msg = sp * sig;
                int rl = wm * 64 + mt * 16 + q * 4 + r;   // local edge row
                int node = rIdx[rl];
                atomicAdd(out + (size_t)node * NODE_DIM + col, msg);
            }
        }
    }
}

extern "C" void kernel_launch(void* const* d_in, const int* in_sizes, int n_in,
                              void* d_out, int out_size, void* d_ws, size_t ws_size,
                              hipStream_t stream) {
    const float* x  = (const float*)d_in[0];
    const int*   ei = (const int*)d_in[1];
    const float* ef = (const float*)d_in[2];
    const float* Wv = (const float*)d_in[3];
    const float* bv = (const float*)d_in[4];
    const float* Wm = (const float*)d_in[5];
    const float* bm = (const float*)d_in[6];
    float* out = (float*)d_out;

    unsigned short* xh = (unsigned short*)d_ws;                        // 12.8 MB
    unsigned short* Wc = (unsigned short*)((char*)d_ws + 12800000);    // 160 KB

    hipMemsetAsync(d_out, 0, (size_t)NN_NODES * NODE_DIM * sizeof(float), stream);

    const int n4 = (NN_NODES * NODE_DIM) / 4;   // 1,600,000
    cast_x_kernel<<<(n4 + 255) / 256, 256, 0, stream>>>(x, xh, n4);
    cast_w_kernel<<<(20480 + 255) / 256, 256, 0, stream>>>(Wv, Wm, Wc);

    cgc_main<<<E_EDGES / BM, THREADS, 0, stream>>>(xh, ei, ef, Wc, bv, bm, out);
}

// Round 2
// 595.796 us; speedup vs baseline: 1.2812x; 1.2812x over previous
//
#include <hip/hip_runtime.h>
#include <hip/hip_bf16.h>

#define E_EDGES   800000
#define NN_NODES  50000
#define NODE_DIM  128
#define EDGE_DIM  64
#define KDIM      320
#define NTOT      256      // val(128) || gate(128)
#define BM        128      // edges per block
#define BK        64       // K chunk
#define SA        72       // padded LDS row stride in f16 elems (144 B = 36 dwords)
#define THREADS   512

typedef _Float16 half8 __attribute__((ext_vector_type(8)));
typedef float    f32x4 __attribute__((ext_vector_type(4)));

__device__ __forceinline__ unsigned short f2h(float f) {
    _Float16 h = (_Float16)f;
    return __builtin_bit_cast(unsigned short, h);
}

// ---- cast x (N_NODES x 128) and W_val||W_mul (256 x 320) fp32 -> f16, one launch ----
// units of float4; [0, n4x) -> x, [n4x, n4x+n4w) -> W combined
__global__ void cast_all_kernel(const float* __restrict__ x,
                                const float* __restrict__ wv,
                                const float* __restrict__ wm,
                                unsigned short* __restrict__ xh,
                                unsigned short* __restrict__ wc) {
    const int n4x = (NN_NODES * NODE_DIM) / 4;        // 1,600,000
    const int n4h = (NODE_DIM * KDIM) / 4;            // 10,240
    int i = blockIdx.x * blockDim.x + threadIdx.x;
    const float* src;
    unsigned short* dst;
    int j;
    if (i < n4x) { src = x; dst = xh; j = i; }
    else {
        int k = i - n4x;
        if (k >= 2 * n4h) return;
        dst = wc; j = k;
        src = (k < n4h) ? wv : wm;
        if (k >= n4h) { src = wm; j = k - n4h; }
        dst = wc; // offset handled below
        float4 f = ((const float4*)src)[j];
        ushort4 o;
        o.x = f2h(f.x); o.y = f2h(f.y); o.z = f2h(f.z); o.w = f2h(f.w);
        ((ushort4*)wc)[k] = o;
        return;
    }
    float4 f = ((const float4*)src)[j];
    ushort4 o;
    o.x = f2h(f.x); o.y = f2h(f.y); o.z = f2h(f.z); o.w = f2h(f.w);
    ((ushort4*)dst)[j] = o;
}

// ---- fused gather + dual-GEMM + softplus*sigmoid + atomic scatter ----
// __launch_bounds__(512, 4): 4 waves/SIMD min -> caps unified VGPR+AGPR at 128/wave
// so TWO blocks co-reside per CU (R1 had 132 regs -> 1 block/CU -> 25% occupancy,
// barrier-serialized staging/compute).
__global__ void __launch_bounds__(THREADS, 4)
cgc_main(const unsigned short* __restrict__ xh,   // [NN][128] f16 bits
         const int* __restrict__ ei,              // [2][E]
         const float* __restrict__ ef,            // [E][64] fp32
         const unsigned short* __restrict__ Wc,   // [256][320] f16 bits
         const float* __restrict__ bval,          // [128]
         const float* __restrict__ bmul,          // [128]
         float* __restrict__ out)                 // [NN][128] fp32 (zeroed)
{
    __shared__ unsigned short As[BM * SA];    // 18432 B
    __shared__ unsigned short Bs[NTOT * SA];  // 36864 B
    __shared__ int sIdx[BM];
    __shared__ int rIdx[BM];

    const int tid  = threadIdx.x;
    const int e0   = blockIdx.x * BM;
    const int lane = tid & 63;
    const int wid  = tid >> 6;      // 0..7
    const int wm   = wid & 1;       // M half: rows [wm*64, wm*64+64)
    const int wn   = wid >> 1;      // 0..3: N strip of 32 output cols
    const int q    = lane >> 4;     // quad
    const int l16  = lane & 15;

    if (tid < BM) {
        sIdx[tid] = ei[e0 + tid];
        rIdx[tid] = ei[E_EDGES + e0 + tid];
    }

    f32x4 acc[4][4];
    const f32x4 zero4 = {0.f, 0.f, 0.f, 0.f};
#pragma unroll
    for (int mt = 0; mt < 4; ++mt)
#pragma unroll
        for (int nt = 0; nt < 4; ++nt) acc[mt][nt] = zero4;

    for (int c = 0; c < 5; ++c) {
        __syncthreads();   // idx ready (c=0) / prev compute done reading LDS
        // ---- stage A chunk: 128 rows x 64 k (f16) ----
        if (c < 4) {
            const int kcol = (c & 1) * 64;   // column offset within x row
#pragma unroll
            for (int i = 0; i < 2; ++i) {
                int u = tid + i * THREADS;   // 0..1023
                int row = u >> 3, seg = u & 7;
                int node = (c < 2) ? sIdx[row] : rIdx[row];
                uint4 v = *(const uint4*)(xh + (size_t)node * NODE_DIM + kcol + seg * 8);
                *(uint4*)(&As[row * SA + seg * 8]) = v;
            }
        } else {
            // edge_ft: fp32 -> f16 convert on the fly
#pragma unroll
            for (int i = 0; i < 2; ++i) {
                int u = tid + i * THREADS;   // 0..1023 ; 8 floats per unit
                int row = u >> 3, seg = u & 7;
                const float* s = ef + (size_t)(e0 + row) * EDGE_DIM + seg * 8;
                float4 f0 = ((const float4*)s)[0];
                float4 f1 = ((const float4*)s)[1];
                uint4 v;
                v.x = (unsigned)f2h(f0.x) | ((unsigned)f2h(f0.y) << 16);
                v.y = (unsigned)f2h(f0.z) | ((unsigned)f2h(f0.w) << 16);
                v.z = (unsigned)f2h(f1.x) | ((unsigned)f2h(f1.y) << 16);
                v.w = (unsigned)f2h(f1.z) | ((unsigned)f2h(f1.w) << 16);
                *(uint4*)(&As[row * SA + seg * 8]) = v;
            }
        }
        // ---- stage B chunk: 256 rows x 64 k (f16, from L2-resident Wc) ----
        {
            const int kOff = c * BK;
#pragma unroll
            for (int i = 0; i < 4; ++i) {
                int u = tid + i * THREADS;   // 0..2047
                int n = u >> 3, seg = u & 7;
                uint4 v = *(const uint4*)(Wc + n * KDIM + kOff + seg * 8);
                *(uint4*)(&Bs[n * SA + seg * 8]) = v;
            }
        }
        __syncthreads();
        // ---- compute: 2 k-steps x 16 mfma ----
#pragma unroll
        for (int ks = 0; ks < BK; ks += 32) {
            half8 a[4], b[4];
#pragma unroll
            for (int mt = 0; mt < 4; ++mt)
                a[mt] = *(const half8*)(&As[(wm * 64 + mt * 16 + l16) * SA + ks + q * 8]);
            const int nb0 = wn * 32;
            const int nbase[4] = { nb0, nb0 + 16, 128 + nb0, 128 + nb0 + 16 };
#pragma unroll
            for (int nt = 0; nt < 4; ++nt)
                b[nt] = *(const half8*)(&Bs[(nbase[nt] + l16) * SA + ks + q * 8]);
#pragma unroll
            for (int mt = 0; mt < 4; ++mt)
#pragma unroll
                for (int nt = 0; nt < 4; ++nt)
                    acc[mt][nt] = __builtin_amdgcn_mfma_f32_16x16x32_f16(
                        a[mt], b[nt], acc[mt][nt], 0, 0, 0);
        }
    }

    // ---- epilogue: msg = softplus(val+bv) * sigmoid(gate+bm); atomic scatter ----
    // Fast hardware transcendentals (v_exp_f32 / v_log_f32 / v_rcp_f32):
    //   softplus(v) = max(v,0) + log(1 + exp(-|v|))   (stable, exp arg <= 0)
    //   sigmoid(g)  = rcp(1 + exp(-g))
    // approx error ~1e-5, threshold is 0.635.
#pragma unroll
    for (int ct = 0; ct < 2; ++ct) {
        const int col = wn * 32 + ct * 16 + l16;
        const float bv = bval[col];
        const float bm = bmul[col];
#pragma unroll
        for (int mt = 0; mt < 4; ++mt) {
#pragma unroll
            for (int r = 0; r < 4; ++r) {
                float v = acc[mt][ct][r] + bv;
                float g = acc[mt][ct + 2][r] + bm;
                float sp  = fmaxf(v, 0.f) + __logf(1.f + __expf(-fabsf(v)));
                float sig = __builtin_amdgcn_rcpf(1.f + __expf(-g));
                float msg = sp * sig;
                int rl = wm * 64 + mt * 16 + q * 4 + r;   // local edge row
                int node = rIdx[rl];
                atomicAdd(out + (size_t)node * NODE_DIM + col, msg);
            }
        }
    }
}

extern "C" void kernel_launch(void* const* d_in, const int* in_sizes, int n_in,
                              void* d_out, int out_size, void* d_ws, size_t ws_size,
                              hipStream_t stream) {
    const float* x  = (const float*)d_in[0];
    const int*   ei = (const int*)d_in[1];
    const float* ef = (const float*)d_in[2];
    const float* Wv = (const float*)d_in[3];
    const float* bv = (const float*)d_in[4];
    const float* Wm = (const float*)d_in[5];
    const float* bm = (const float*)d_in[6];
    float* out = (float*)d_out;

    unsigned short* xh = (unsigned short*)d_ws;                        // 12.8 MB
    unsigned short* Wc = (unsigned short*)((char*)d_ws + 12800000);    // 160 KB

    hipMemsetAsync(d_out, 0, (size_t)NN_NODES * NODE_DIM * sizeof(float), stream);

    const int n4x = (NN_NODES * NODE_DIM) / 4;            // 1,600,000
    const int n4w = (2 * NODE_DIM * KDIM) / 4;            // 20,480
    const int total = n4x + n4w;
    cast_all_kernel<<<(total + 255) / 256, 256, 0, stream>>>(x, Wv, Wm, xh, Wc);

    cgc_main<<<E_EDGES / BM, THREADS, 0, stream>>>(xh, ei, ef, Wc, bv, bm, out);
}